// Round 2
// baseline (1140.556 us; speedup 1.0000x reference)
//
#include <hip/hip_runtime.h>

// ---------------------------------------------------------------------------
// Two stacked SwinV2 shifted-window attentions, MI355X/gfx950.
// Pipeline: t_in (NCHW->NHWC) -> [k_attn -> k_proj] x2 -> t_out (NHWC->NCHW)
// k_setup converts weights to bf16 + computes 16*sigmoid(cpb MLP) tables;
// k_expand expands them to dense BT[8][64][64].
// k_attn: 512 threads (8 waves), 2 blocks/CU (16 waves/CU). Per head-pair p:
//   GEMM split (row-half x section), norms via shfl butterfly in epilogue,
//   attention split (row-group x head). 2 barriers per p-iteration.
// ---------------------------------------------------------------------------

typedef short bf16x8 __attribute__((ext_vector_type(8)));
typedef float f32x4 __attribute__((ext_vector_type(4)));

__device__ __forceinline__ unsigned short f2bf(float f) {
    union { float f; unsigned int u; } v; v.f = f;
    return (unsigned short)((v.u + 0x7fffu + ((v.u >> 16) & 1u)) >> 16);
}
__device__ __forceinline__ f32x4 mfma_bf16(bf16x8 a, bf16x8 b, f32x4 c) {
    return __builtin_amdgcn_mfma_f32_16x16x32_bf16(a, b, c, 0, 0, 0);
}

// region id for the swin shifted mask (pH=pW=64, ws=8, shift=4).
__device__ __forceinline__ int region_of(int wh, int ww, int t) {
    int th = t >> 3, tw = t & 7;
    int rh = (wh == 7) ? ((th < 4) ? 1 : 2) : 0;
    int rw = (ww == 7) ? ((tw < 4) ? 1 : 2) : 0;
    return rh * 3 + rw;
}

// ---------------------------------------------------------------------------
__global__ __launch_bounds__(256) void k_setup(
    const float* __restrict__ qkvw1, const float* __restrict__ projw1,
    const float* __restrict__ qkvw2, const float* __restrict__ projw2,
    const float* __restrict__ w1a, const float* __restrict__ b1a, const float* __restrict__ w2a,
    const float* __restrict__ w1b, const float* __restrict__ b1b, const float* __restrict__ w2b,
    unsigned short* __restrict__ qw1, unsigned short* __restrict__ pw1,
    unsigned short* __restrict__ qw2, unsigned short* __restrict__ pw2,
    float* __restrict__ bt1, float* __restrict__ bt2)
{
    int b = blockIdx.x, t = threadIdx.x;
    if (b < 512) {
        int idx = b * 256 + t;
        #pragma unroll
        for (int r = 0; r < 4; r++) {
            int i = idx + r * 131072;
            if (i < 196608)        qw1[i]          = f2bf(qkvw1[i]);
            else if (i < 262144)   pw1[i - 196608] = f2bf(projw1[i - 196608]);
            else if (i < 458752)   qw2[i - 262144] = f2bf(qkvw2[i - 262144]);
            else                   pw2[i - 458752] = f2bf(projw2[i - 458752]);
        }
    } else {
        int a = b - 512;
        const float* w1 = a ? w1b : w1a;
        const float* b1 = a ? b1b : b1a;
        const float* w2 = a ? w2b : w2a;
        float* out = a ? bt2 : bt1;
        int k = t;
        if (k >= 225) return;
        int ih = k / 15, iw = k % 15;
        float v0 = (float)(ih - 7) / 7.0f * 8.0f;
        float v1 = (float)(iw - 7) / 7.0f * 8.0f;
        float t0 = (v0 >= 0.f ? 1.f : -1.f) * log2f(fabsf(v0) + 1.f) / 3.0f;
        float t1 = (v1 >= 0.f ? 1.f : -1.f) * log2f(fabsf(v1) + 1.f) / 3.0f;
        float acc[8] = {0.f, 0.f, 0.f, 0.f, 0.f, 0.f, 0.f, 0.f};
        for (int c = 0; c < 512; c++) {
            float hc = t0 * w1[2 * c] + t1 * w1[2 * c + 1] + b1[c];
            hc = fmaxf(hc, 0.f);
            #pragma unroll
            for (int h = 0; h < 8; h++) acc[h] += hc * w2[h * 512 + c];
        }
        #pragma unroll
        for (int h = 0; h < 8; h++) out[k * 8 + h] = 16.f / (1.f + expf(-acc[h]));
    }
}

// expand bt[225][8] -> BT[8][64][64]  (two tables)
__global__ __launch_bounds__(256) void k_expand(
    const float* __restrict__ bt1, const float* __restrict__ bt2,
    float* __restrict__ BT1, float* __restrict__ BT2)
{
    int idx = blockIdx.x * 256 + threadIdx.x;           // 65536 total
    int a = idx >> 15, rest = idx & 32767;
    int head = rest >> 12, ij = rest & 4095;
    int i = ij >> 6, j = ij & 63;
    int rel = ((i >> 3) - (j >> 3) + 7) * 15 + ((i & 7) - (j & 7) + 7);
    const float* src = a ? bt2 : bt1;
    float* dst = a ? BT2 : BT1;
    dst[head * 4096 + ij] = src[rel * 8 + head];
}

// ---------------------------------------------------------------------------
__global__ __launch_bounds__(256) void t_in(const float* __restrict__ src, float* __restrict__ dst) {
    __shared__ float tile[32][33];
    int img = blockIdx.z, hw0 = blockIdx.x * 32, c0 = blockIdx.y * 32;
    int x = threadIdx.x & 31, y = threadIdx.x >> 5;
    #pragma unroll
    for (int k = 0; k < 4; k++)
        tile[y + k * 8][x] = src[((size_t)img * 256 + c0 + y + k * 8) * 4096 + hw0 + x];
    __syncthreads();
    #pragma unroll
    for (int k = 0; k < 4; k++)
        dst[((size_t)img * 4096 + hw0 + y + k * 8) * 256 + c0 + x] = tile[x][y + k * 8];
}

__global__ __launch_bounds__(256) void t_out(const float* __restrict__ src, float* __restrict__ dst) {
    __shared__ float tile[32][33];
    int img = blockIdx.z, hw0 = blockIdx.x * 32, c0 = blockIdx.y * 32;
    int x = threadIdx.x & 31, y = threadIdx.x >> 5;
    #pragma unroll
    for (int k = 0; k < 4; k++)
        tile[y + k * 8][x] = src[((size_t)img * 4096 + hw0 + y + k * 8) * 256 + c0 + x];
    __syncthreads();
    #pragma unroll
    for (int k = 0; k < 4; k++)
        dst[((size_t)img * 256 + c0 + y + k * 8) * 4096 + hw0 + x] = tile[x][y + k * 8];
}

// ---------------------------------------------------------------------------
// k_attn: one block per window, 512 threads = 8 waves.
// GEMM: wave = (h2 = wv&1 row-half, s = wv>>1 section). Section s owns qk
// col-tiles {2s,2s+1} (q0,q1,k0,k1 for s=0..3) + v tile 8+s (v channels
// s*16..s*16+15 of the head-pair).
// Attention: wave = (g = wv>>1 row-group, hh = wv&1 head within pair).
// ---------------------------------------------------------------------------
__global__ __launch_bounds__(512, 4) void k_attn(
    const float* __restrict__ Xin,           // NHWC f32 [32][64][64][256]
    const unsigned short* __restrict__ Wq,   // qkv_w bf16 [768][256]
    const float* __restrict__ bq,            // qkv_b f32 [768]
    const float* __restrict__ lsc,           // logit_scale [8]
    const float* __restrict__ BT,            // dense bias f32 [8][64][64]
    unsigned short* __restrict__ AO,         // attn_out bf16 [2048][64][256]
    int shift, int masked)
{
    __shared__ __align__(16) unsigned short sX[64 * 264];     // X window bf16      33792 B
    __shared__ __align__(16) unsigned short sQK[64 * 136];    // q0 q1 k0 k1        17408 B
    __shared__ __align__(16) unsigned short sP[2 * 64 * 72];  // probs per head     18432 B
    __shared__ __align__(16) unsigned short sVt[64 * 72];     // V^T [dim][token]    9216 B
    __shared__ float sInv[4 * 64];                            // 1/norm q0q1k0k1     1024 B

    const int tid = threadIdx.x;
    const int wv = tid >> 6, lane = tid & 63, quad = lane >> 4, nn = lane & 15;
    const int win = blockIdx.x;
    const int bt = win >> 6, wh = (win >> 3) & 7, ww = win & 7;
    const f32x4 zero4 = {0.f, 0.f, 0.f, 0.f};

    // ---- stage X window (shift roll folded into the gather) ----
    {
        int tok = tid >> 3, part = tid & 7;
        int h = (wh * 8 + (tok >> 3) + shift) & 63;
        int w = (ww * 8 + (tok & 7) + shift) & 63;
        const float* srcp = Xin + ((size_t)(bt * 4096 + h * 64 + w)) * 256 + part * 32;
        unsigned short* dstp = sX + tok * 264 + part * 32;
        #pragma unroll
        for (int c = 0; c < 32; c += 4) {
            float4 v = *(const float4*)(srcp + c);
            unsigned int p0 = (unsigned int)f2bf(v.x) | ((unsigned int)f2bf(v.y) << 16);
            unsigned int p1 = (unsigned int)f2bf(v.z) | ((unsigned int)f2bf(v.w) << 16);
            uint2 o; o.x = p0; o.y = p1;
            *(uint2*)(dstp + c) = o;
        }
    }
    __syncthreads();

    const int h2 = wv & 1, s = wv >> 1;       // GEMM role
    const int rb = h2 * 32;
    const int kindq = (s < 2);                // q sections keep bias
    const int g = wv >> 1, hh = wv & 1;       // attention role

    for (int p = 0; p < 4; p++) {
        // ===== QKV GEMM: rows rb..rb+31, cols = tiles {2s,2s+1,8+s} =====
        int wrow0 = (s >> 1) * 256 + (2 * p + (s & 1)) * 32 + nn;  // qk tile c=0
        int wrow1 = wrow0 + 16;                                    // qk tile c=1
        int wrowv = 512 + p * 64 + s * 16 + nn;                    // v tile

        f32x4 acc00 = zero4, acc01 = zero4, acc0v = zero4;
        f32x4 acc10 = zero4, acc11 = zero4, acc1v = zero4;
        #pragma unroll
        for (int ks = 0; ks < 8; ks++) {
            bf16x8 a0 = *(const bf16x8*)(sX + (rb + nn) * 264 + ks * 32 + quad * 8);
            bf16x8 a1 = *(const bf16x8*)(sX + (rb + 16 + nn) * 264 + ks * 32 + quad * 8);
            bf16x8 b0 = *(const bf16x8*)(Wq + (size_t)wrow0 * 256 + ks * 32 + quad * 8);
            bf16x8 b1 = *(const bf16x8*)(Wq + (size_t)wrow1 * 256 + ks * 32 + quad * 8);
            bf16x8 bv = *(const bf16x8*)(Wq + (size_t)wrowv * 256 + ks * 32 + quad * 8);
            acc00 = mfma_bf16(a0, b0, acc00);
            acc10 = mfma_bf16(a1, b0, acc10);
            acc01 = mfma_bf16(a0, b1, acc01);
            acc11 = mfma_bf16(a1, b1, acc11);
            acc0v = mfma_bf16(a0, bv, acc0v);
            acc1v = mfma_bf16(a1, bv, acc1v);
        }

        __syncthreads();  // previous attention phase done reading sQK/sVt/sInv

        // ===== epilogue: bias, bf16 -> sQK / sVt, norms via shfl butterfly =====
        {
            float bia0 = kindq ? bq[wrow0] : 0.f;
            float bia1 = kindq ? bq[wrow1] : 0.f;
            float biav = bq[wrowv];
            #pragma unroll
            for (int rt = 0; rt < 2; rt++) {
                const f32x4 A0 = rt ? acc10 : acc00;
                const f32x4 A1 = rt ? acc11 : acc01;
                const f32x4 AV = rt ? acc1v : acc0v;
                int tb = rb + rt * 16 + quad * 4;
                float ss[4];
                #pragma unroll
                for (int r = 0; r < 4; r++) {
                    float v0 = A0[r] + bia0;
                    float v1 = A1[r] + bia1;
                    float vv = AV[r] + biav;
                    sQK[(tb + r) * 136 + s * 32 + nn]      = f2bf(v0);
                    sQK[(tb + r) * 136 + s * 32 + 16 + nn] = f2bf(v1);
                    sVt[(s * 16 + nn) * 72 + tb + r]       = f2bf(vv);
                    ss[r] = v0 * v0 + v1 * v1;
                }
                #pragma unroll
                for (int r = 0; r < 4; r++) {
                    ss[r] += __shfl_xor(ss[r], 1);
                    ss[r] += __shfl_xor(ss[r], 2);
                    ss[r] += __shfl_xor(ss[r], 4);
                    ss[r] += __shfl_xor(ss[r], 8);
                }
                if (nn < 4)
                    sInv[s * 64 + tb + nn] = 1.f / fmaxf(sqrtf(ss[nn]), 1e-12f);
            }
        }
        __syncthreads();

        // ===== attention: wave (g, hh) does rows g*16..+15 of head 2p+hh =====
        {
            const int head = 2 * p + hh;
            const float scale = __expf(fminf(lsc[head], 4.605170185988092f)); // ln(100)

            bf16x8 aq = *(const bf16x8*)(sQK + (g * 16 + nn) * 136 + hh * 32 + quad * 8);
            f32x4 S[4];
            #pragma unroll
            for (int ct = 0; ct < 4; ct++) {
                bf16x8 bk = *(const bf16x8*)(sQK + (ct * 16 + nn) * 136 + 64 + hh * 32 + quad * 8);
                S[ct] = mfma_bf16(aq, bk, zero4);
            }

            const int i_base = g * 16 + quad * 4;
            float invq[4];
            int ri[4];
            #pragma unroll
            for (int r = 0; r < 4; r++) {
                invq[r] = sInv[hh * 64 + i_base + r];
                ri[r] = masked ? region_of(wh, ww, i_base + r) : 0;
            }
            const float* btp = BT + head * 4096;
            const float* invk = sInv + (2 + hh) * 64;

            float rowm[4] = {-3.0e38f, -3.0e38f, -3.0e38f, -3.0e38f};
            #pragma unroll
            for (int ct = 0; ct < 4; ct++) {
                int j = ct * 16 + nn;
                float ivk = invk[j];
                int rj = masked ? region_of(wh, ww, j) : 0;
                #pragma unroll
                for (int r = 0; r < 4; r++) {
                    float v = S[ct][r] * invq[r] * ivk * scale + btp[(i_base + r) * 64 + j];
                    if (masked && (ri[r] != rj)) v += -100.f;
                    S[ct][r] = v;
                    rowm[r] = fmaxf(rowm[r], v);
                }
            }
            #pragma unroll
            for (int r = 0; r < 4; r++) {
                float m = rowm[r];
                m = fmaxf(m, __shfl_xor(m, 1));
                m = fmaxf(m, __shfl_xor(m, 2));
                m = fmaxf(m, __shfl_xor(m, 4));
                m = fmaxf(m, __shfl_xor(m, 8));
                rowm[r] = m;
            }
            float rsum[4] = {0.f, 0.f, 0.f, 0.f};
            #pragma unroll
            for (int ct = 0; ct < 4; ct++)
                #pragma unroll
                for (int r = 0; r < 4; r++) {
                    float e = __expf(S[ct][r] - rowm[r]);
                    S[ct][r] = e;
                    rsum[r] += e;
                }
            #pragma unroll
            for (int r = 0; r < 4; r++) {
                float sm = rsum[r];
                sm += __shfl_xor(sm, 1);
                sm += __shfl_xor(sm, 2);
                sm += __shfl_xor(sm, 4);
                sm += __shfl_xor(sm, 8);
                rsum[r] = 1.f / sm;
            }
            unsigned short* sPh = sP + hh * 4608;
            #pragma unroll
            for (int ct = 0; ct < 4; ct++)
                #pragma unroll
                for (int r = 0; r < 4; r++)
                    sPh[(i_base + r) * 72 + ct * 16 + nn] = f2bf(S[ct][r] * rsum[r]);

            // ----- O = P V -----
            bf16x8 ap0 = *(const bf16x8*)(sPh + (g * 16 + nn) * 72 + quad * 8);
            bf16x8 ap1 = *(const bf16x8*)(sPh + (g * 16 + nn) * 72 + 32 + quad * 8);
            #pragma unroll
            for (int ct2 = 0; ct2 < 2; ct2++) {
                bf16x8 bv0 = *(const bf16x8*)(sVt + (hh * 32 + ct2 * 16 + nn) * 72 + quad * 8);
                bf16x8 bv1 = *(const bf16x8*)(sVt + (hh * 32 + ct2 * 16 + nn) * 72 + 32 + quad * 8);
                f32x4 O = mfma_bf16(ap0, bv0, zero4);
                O = mfma_bf16(ap1, bv1, O);
                #pragma unroll
                for (int r = 0; r < 4; r++)
                    AO[((size_t)win * 64 + i_base + r) * 256 + head * 32 + ct2 * 16 + nn] = f2bf(O[r]);
            }
        }
    }
}

// ---------------------------------------------------------------------------
// k_proj: one block per window. out = attn_out @ proj_w^T + proj_b + residual.
// ---------------------------------------------------------------------------
__global__ __launch_bounds__(256, 4) void k_proj(
    const unsigned short* __restrict__ AO,
    const unsigned short* __restrict__ Wp,
    const float* __restrict__ bp,
    const float* __restrict__ Xres,
    float* __restrict__ Xout,
    int shift)
{
    __shared__ __align__(16) unsigned short sO[64 * 264];
    const int tid = threadIdx.x;
    const int wv = tid >> 6, lane = tid & 63, quad = lane >> 4, nn = lane & 15;
    const int win = blockIdx.x;
    const int bt = win >> 6, wh = (win >> 3) & 7, ww = win & 7;
    const f32x4 zero4 = {0.f, 0.f, 0.f, 0.f};

    {
        int tok = tid >> 2, part = tid & 3;
        const unsigned short* srcp = AO + ((size_t)win * 64 + tok) * 256 + part * 64;
        unsigned short* dstp = sO + tok * 264 + part * 64;
        #pragma unroll
        for (int c = 0; c < 64; c += 8)
            *(uint4*)(dstp + c) = *(const uint4*)(srcp + c);
    }
    __syncthreads();

    f32x4 acc[4][4];
    #pragma unroll
    for (int rt = 0; rt < 4; rt++)
        #pragma unroll
        for (int c = 0; c < 4; c++) acc[rt][c] = zero4;

    int wrow[4];
    #pragma unroll
    for (int c = 0; c < 4; c++) wrow[c] = (wv * 4 + c) * 16 + nn;

    #pragma unroll
    for (int ks = 0; ks < 8; ks++) {
        bf16x8 a[4], b[4];
        #pragma unroll
        for (int rt = 0; rt < 4; rt++)
            a[rt] = *(const bf16x8*)(sO + (rt * 16 + nn) * 264 + ks * 32 + quad * 8);
        #pragma unroll
        for (int c = 0; c < 4; c++)
            b[c] = *(const bf16x8*)(Wp + (size_t)wrow[c] * 256 + ks * 32 + quad * 8);
        #pragma unroll
        for (int rt = 0; rt < 4; rt++)
            #pragma unroll
            for (int c = 0; c < 4; c++)
                acc[rt][c] = mfma_bf16(a[rt], b[c], acc[rt][c]);
    }

    #pragma unroll
    for (int c = 0; c < 4; c++) {
        int chan = wrow[c];
        float bias = bp[chan];
        #pragma unroll
        for (int rt = 0; rt < 4; rt++)
            #pragma unroll
            for (int r = 0; r < 4; r++) {
                int tok = rt * 16 + quad * 4 + r;
                int h = (wh * 8 + (tok >> 3) + shift) & 63;
                int w = (ww * 8 + (tok & 7) + shift) & 63;
                size_t idx = ((size_t)(bt * 4096 + h * 64 + w)) * 256 + chan;
                Xout[idx] = acc[rt][c][r] + bias + Xres[idx];
            }
    }
}

// ---------------------------------------------------------------------------
extern "C" void kernel_launch(void* const* d_in, const int* in_sizes, int n_in,
                              void* d_out, int out_size, void* d_ws, size_t ws_size,
                              hipStream_t stream) {
    (void)in_sizes; (void)n_in; (void)out_size; (void)ws_size;

    const float* src        = (const float*)d_in[0];
    const float* a1_qkv_w   = (const float*)d_in[1];
    const float* a1_qkv_b   = (const float*)d_in[2];
    const float* a1_proj_w  = (const float*)d_in[3];
    const float* a1_proj_b  = (const float*)d_in[4];
    const float* a1_ls      = (const float*)d_in[5];
    const float* a1_w1      = (const float*)d_in[6];
    const float* a1_b1      = (const float*)d_in[7];
    const float* a1_w2      = (const float*)d_in[8];
    const float* a2_qkv_w   = (const float*)d_in[9];
    const float* a2_qkv_b   = (const float*)d_in[10];
    const float* a2_proj_w  = (const float*)d_in[11];
    const float* a2_proj_b  = (const float*)d_in[12];
    const float* a2_ls      = (const float*)d_in[13];
    const float* a2_w1      = (const float*)d_in[14];
    const float* a2_b1      = (const float*)d_in[15];
    const float* a2_w2      = (const float*)d_in[16];

    char* ws = (char*)d_ws;
    const size_t SZ_X = 134217728;  // 32*4096*256*4
    float* X0 = (float*)(ws);
    float* X1 = (float*)(ws + SZ_X);
    unsigned short* AO  = (unsigned short*)(ws + 2 * SZ_X);          // 67108864 B
    unsigned short* qw1 = (unsigned short*)(ws + 2 * SZ_X + 67108864);
    unsigned short* qw2 = qw1 + 196608;
    unsigned short* pw1 = qw2 + 196608;
    unsigned short* pw2 = pw1 + 65536;
    float* bt1 = (float*)(pw2 + 65536);
    float* bt2 = bt1 + 1800;
    float* BT1 = bt2 + 1800;
    float* BT2 = BT1 + 32768;

    k_setup<<<514, 256, 0, stream>>>(a1_qkv_w, a1_proj_w, a2_qkv_w, a2_proj_w,
                                     a1_w1, a1_b1, a1_w2, a2_w1, a2_b1, a2_w2,
                                     qw1, pw1, qw2, pw2, bt1, bt2);
    k_expand<<<256, 256, 0, stream>>>(bt1, bt2, BT1, BT2);
    t_in<<<dim3(128, 8, 32), 256, 0, stream>>>(src, X0);

    // pass 1: no shift, no mask
    k_attn<<<2048, 512, 0, stream>>>(X0, qw1, a1_qkv_b, a1_ls, BT1, AO, 0, 0);
    k_proj<<<2048, 256, 0, stream>>>(AO, pw1, a1_proj_b, X0, X1, 0);
    // pass 2: shift 4, masked
    k_attn<<<2048, 512, 0, stream>>>(X1, qw2, a2_qkv_b, a2_ls, BT2, AO, 4, 1);
    k_proj<<<2048, 256, 0, stream>>>(AO, pw2, a2_proj_b, X1, X0, 4);

    t_out<<<dim3(128, 8, 32), 256, 0, stream>>>(X0, (float*)d_out);
}

// Round 3
// 1109.096 us; speedup vs baseline: 1.0284x; 1.0284x over previous
//
#include <hip/hip_runtime.h>

// ---------------------------------------------------------------------------
// Two stacked SwinV2 shifted-window attentions, MI355X/gfx950.
// t_in (NCHW->NHWC) -> [k_attn -> k_proj] x2 -> t_out (NHWC->NCHW)
// R3: explicit register prefetch (double-buffered W frags, hoisted BT/bias
// loads) to fix memory-latency serialization seen in R2 (VGPR=56, all pipes
// <30% busy). k_cpb stages MLP weights in LDS.
// ---------------------------------------------------------------------------

typedef short bf16x8 __attribute__((ext_vector_type(8)));
typedef float f32x4 __attribute__((ext_vector_type(4)));

__device__ __forceinline__ unsigned short f2bf(float f) {
    union { float f; unsigned int u; } v; v.f = f;
    return (unsigned short)((v.u + 0x7fffu + ((v.u >> 16) & 1u)) >> 16);
}
__device__ __forceinline__ f32x4 mfma_bf16(bf16x8 a, bf16x8 b, f32x4 c) {
    return __builtin_amdgcn_mfma_f32_16x16x32_bf16(a, b, c, 0, 0, 0);
}

__device__ __forceinline__ int region_of(int wh, int ww, int t) {
    int th = t >> 3, tw = t & 7;
    int rh = (wh == 7) ? ((th < 4) ? 1 : 2) : 0;
    int rw = (ww == 7) ? ((tw < 4) ? 1 : 2) : 0;
    return rh * 3 + rw;
}

// ---------------------------------------------------------------------------
// weight f32 -> bf16 conversion (512 blocks)
__global__ __launch_bounds__(256) void k_setup(
    const float* __restrict__ qkvw1, const float* __restrict__ projw1,
    const float* __restrict__ qkvw2, const float* __restrict__ projw2,
    unsigned short* __restrict__ qw1, unsigned short* __restrict__ pw1,
    unsigned short* __restrict__ qw2, unsigned short* __restrict__ pw2)
{
    int idx = blockIdx.x * 256 + threadIdx.x;
    #pragma unroll
    for (int r = 0; r < 4; r++) {
        int i = idx + r * 131072;
        if (i < 196608)        qw1[i]          = f2bf(qkvw1[i]);
        else if (i < 262144)   pw1[i - 196608] = f2bf(projw1[i - 196608]);
        else if (i < 458752)   qw2[i - 262144] = f2bf(qkvw2[i - 262144]);
        else                   pw2[i - 458752] = f2bf(projw2[i - 458752]);
    }
}

// cpb MLP: 2 blocks (one per attention), weights staged in LDS
__global__ __launch_bounds__(256) void k_cpb(
    const float* __restrict__ w1a, const float* __restrict__ b1a, const float* __restrict__ w2a,
    const float* __restrict__ w1b, const float* __restrict__ b1b, const float* __restrict__ w2b,
    float* __restrict__ bt1, float* __restrict__ bt2)
{
    __shared__ float sw[5632];  // w1[1024] | b1[512] | w2[4096]
    int a = blockIdx.x, tid = threadIdx.x;
    const float* w1 = a ? w1b : w1a;
    const float* b1 = a ? b1b : b1a;
    const float* w2 = a ? w2b : w2a;
    float* out = a ? bt2 : bt1;
    for (int i = tid; i < 1024; i += 256) sw[i] = w1[i];
    for (int i = tid; i < 512; i += 256)  sw[1024 + i] = b1[i];
    for (int i = tid; i < 4096; i += 256) sw[1536 + i] = w2[i];
    __syncthreads();
    int k = tid;
    if (k >= 225) return;
    int ih = k / 15, iw = k % 15;
    float v0 = (float)(ih - 7) / 7.0f * 8.0f;
    float v1 = (float)(iw - 7) / 7.0f * 8.0f;
    float t0 = (v0 >= 0.f ? 1.f : -1.f) * log2f(fabsf(v0) + 1.f) / 3.0f;
    float t1 = (v1 >= 0.f ? 1.f : -1.f) * log2f(fabsf(v1) + 1.f) / 3.0f;
    float acc[8] = {0.f, 0.f, 0.f, 0.f, 0.f, 0.f, 0.f, 0.f};
    for (int c = 0; c < 512; c++) {
        float hc = t0 * sw[2 * c] + t1 * sw[2 * c + 1] + sw[1024 + c];
        hc = fmaxf(hc, 0.f);
        #pragma unroll
        for (int h = 0; h < 8; h++) acc[h] += hc * sw[1536 + h * 512 + c];
    }
    #pragma unroll
    for (int h = 0; h < 8; h++) out[k * 8 + h] = 16.f / (1.f + expf(-acc[h]));
}

// expand bt[225][8] -> BT[8][64][64]
__global__ __launch_bounds__(256) void k_expand(
    const float* __restrict__ bt1, const float* __restrict__ bt2,
    float* __restrict__ BT1, float* __restrict__ BT2)
{
    int idx = blockIdx.x * 256 + threadIdx.x;
    int a = idx >> 15, rest = idx & 32767;
    int head = rest >> 12, ij = rest & 4095;
    int i = ij >> 6, j = ij & 63;
    int rel = ((i >> 3) - (j >> 3) + 7) * 15 + ((i & 7) - (j & 7) + 7);
    const float* src = a ? bt2 : bt1;
    float* dst = a ? BT2 : BT1;
    dst[head * 4096 + ij] = src[rel * 8 + head];
}

// ---------------------------------------------------------------------------
__global__ __launch_bounds__(256) void t_in(const float* __restrict__ src, float* __restrict__ dst) {
    __shared__ float tile[32][33];
    int img = blockIdx.z, hw0 = blockIdx.x * 32, c0 = blockIdx.y * 32;
    int x = threadIdx.x & 31, y = threadIdx.x >> 5;
    #pragma unroll
    for (int k = 0; k < 4; k++)
        tile[y + k * 8][x] = src[((size_t)img * 256 + c0 + y + k * 8) * 4096 + hw0 + x];
    __syncthreads();
    #pragma unroll
    for (int k = 0; k < 4; k++)
        dst[((size_t)img * 4096 + hw0 + y + k * 8) * 256 + c0 + x] = tile[x][y + k * 8];
}

__global__ __launch_bounds__(256) void t_out(const float* __restrict__ src, float* __restrict__ dst) {
    __shared__ float tile[32][33];
    int img = blockIdx.z, hw0 = blockIdx.x * 32, c0 = blockIdx.y * 32;
    int x = threadIdx.x & 31, y = threadIdx.x >> 5;
    #pragma unroll
    for (int k = 0; k < 4; k++)
        tile[y + k * 8][x] = src[((size_t)img * 4096 + hw0 + y + k * 8) * 256 + c0 + x];
    __syncthreads();
    #pragma unroll
    for (int k = 0; k < 4; k++)
        dst[((size_t)img * 256 + c0 + y + k * 8) * 4096 + hw0 + x] = tile[x][y + k * 8];
}

// ---------------------------------------------------------------------------
// k_attn: one block per window, 512 threads = 8 waves, 2 blocks/CU.
// GEMM role: wave = (h2 row-half, s section); attention role: (g row-group, hh head).
// ---------------------------------------------------------------------------
__global__ __launch_bounds__(512, 4) void k_attn(
    const float* __restrict__ Xin,
    const unsigned short* __restrict__ Wq,
    const float* __restrict__ bq,
    const float* __restrict__ lsc,
    const float* __restrict__ BT,
    unsigned short* __restrict__ AO,
    int shift, int masked)
{
    __shared__ __align__(16) unsigned short sX[64 * 264];
    __shared__ __align__(16) unsigned short sQK[64 * 136];
    __shared__ __align__(16) unsigned short sP[2 * 64 * 72];
    __shared__ __align__(16) unsigned short sVt[64 * 72];
    __shared__ float sInv[4 * 64];

    const int tid = threadIdx.x;
    const int wv = tid >> 6, lane = tid & 63, quad = lane >> 4, nn = lane & 15;
    const int win = blockIdx.x;
    const int bt = win >> 6, wh = (win >> 3) & 7, ww = win & 7;
    const f32x4 zero4 = {0.f, 0.f, 0.f, 0.f};

    // ---- stage X window (shift roll folded into gather) ----
    {
        int tok = tid >> 3, part = tid & 7;
        int h = (wh * 8 + (tok >> 3) + shift) & 63;
        int w = (ww * 8 + (tok & 7) + shift) & 63;
        const float* srcp = Xin + ((size_t)(bt * 4096 + h * 64 + w)) * 256 + part * 32;
        unsigned short* dstp = sX + tok * 264 + part * 32;
        float4 v0 = *(const float4*)(srcp + 0);
        float4 v1 = *(const float4*)(srcp + 4);
        float4 v2 = *(const float4*)(srcp + 8);
        float4 v3 = *(const float4*)(srcp + 12);
        float4 v4 = *(const float4*)(srcp + 16);
        float4 v5 = *(const float4*)(srcp + 20);
        float4 v6 = *(const float4*)(srcp + 24);
        float4 v7 = *(const float4*)(srcp + 28);
        float4 vv[8] = {v0, v1, v2, v3, v4, v5, v6, v7};
        #pragma unroll
        for (int c = 0; c < 8; c++) {
            uint2 o;
            o.x = (unsigned int)f2bf(vv[c].x) | ((unsigned int)f2bf(vv[c].y) << 16);
            o.y = (unsigned int)f2bf(vv[c].z) | ((unsigned int)f2bf(vv[c].w) << 16);
            *(uint2*)(dstp + c * 4) = o;
        }
    }
    __syncthreads();

    const int h2 = wv & 1, s = wv >> 1;
    const int rb = h2 * 32;
    const int kindq = (s < 2);
    const int g = wv >> 1, hh = wv & 1;

    for (int p = 0; p < 4; p++) {
        // ===== QKV GEMM: double-buffered W prefetch (2-ks batches) =====
        int wrow0 = (s >> 1) * 256 + (2 * p + (s & 1)) * 32 + nn;
        int wrow1 = wrow0 + 16;
        int wrowv = 512 + p * 64 + s * 16 + nn;
        const unsigned short* w0p = Wq + (size_t)wrow0 * 256 + quad * 8;
        const unsigned short* w1p = Wq + (size_t)wrow1 * 256 + quad * 8;
        const unsigned short* wvp = Wq + (size_t)wrowv * 256 + quad * 8;

        bf16x8 WB[2][6];
        #pragma unroll
        for (int kk = 0; kk < 2; kk++) {
            WB[0][kk * 3 + 0] = *(const bf16x8*)(w0p + kk * 32);
            WB[0][kk * 3 + 1] = *(const bf16x8*)(w1p + kk * 32);
            WB[0][kk * 3 + 2] = *(const bf16x8*)(wvp + kk * 32);
        }
        float bia0 = kindq ? bq[wrow0] : 0.f;
        float bia1 = kindq ? bq[wrow1] : 0.f;
        float biav = bq[wrowv];

        f32x4 acc00 = zero4, acc01 = zero4, acc0v = zero4;
        f32x4 acc10 = zero4, acc11 = zero4, acc1v = zero4;
        #pragma unroll
        for (int kg = 0; kg < 4; kg++) {
            const int cb = kg & 1, nb = cb ^ 1;
            if (kg < 3) {
                #pragma unroll
                for (int kk = 0; kk < 2; kk++) {
                    int ks = (kg + 1) * 2 + kk;
                    WB[nb][kk * 3 + 0] = *(const bf16x8*)(w0p + ks * 32);
                    WB[nb][kk * 3 + 1] = *(const bf16x8*)(w1p + ks * 32);
                    WB[nb][kk * 3 + 2] = *(const bf16x8*)(wvp + ks * 32);
                }
            }
            #pragma unroll
            for (int kk = 0; kk < 2; kk++) {
                int ks = kg * 2 + kk;
                bf16x8 a0 = *(const bf16x8*)(sX + (rb + nn) * 264 + ks * 32 + quad * 8);
                bf16x8 a1 = *(const bf16x8*)(sX + (rb + 16 + nn) * 264 + ks * 32 + quad * 8);
                acc00 = mfma_bf16(a0, WB[cb][kk * 3 + 0], acc00);
                acc10 = mfma_bf16(a1, WB[cb][kk * 3 + 0], acc10);
                acc01 = mfma_bf16(a0, WB[cb][kk * 3 + 1], acc01);
                acc11 = mfma_bf16(a1, WB[cb][kk * 3 + 1], acc11);
                acc0v = mfma_bf16(a0, WB[cb][kk * 3 + 2], acc0v);
                acc1v = mfma_bf16(a1, WB[cb][kk * 3 + 2], acc1v);
            }
        }

        __syncthreads();  // previous attention phase done with sQK/sVt/sInv

        // ===== epilogue: bias, bf16 pack, norms via shfl butterfly =====
        #pragma unroll
        for (int rt = 0; rt < 2; rt++) {
            const f32x4 A0 = rt ? acc10 : acc00;
            const f32x4 A1 = rt ? acc11 : acc01;
            const f32x4 AV = rt ? acc1v : acc0v;
            int tb = rb + rt * 16 + quad * 4;
            float ss[4];
            #pragma unroll
            for (int r = 0; r < 4; r++) {
                float v0 = A0[r] + bia0;
                float v1 = A1[r] + bia1;
                float vv = AV[r] + biav;
                sQK[(tb + r) * 136 + s * 32 + nn]      = f2bf(v0);
                sQK[(tb + r) * 136 + s * 32 + 16 + nn] = f2bf(v1);
                sVt[(s * 16 + nn) * 72 + tb + r]       = f2bf(vv);
                ss[r] = v0 * v0 + v1 * v1;
            }
            #pragma unroll
            for (int r = 0; r < 4; r++) {
                ss[r] += __shfl_xor(ss[r], 1);
                ss[r] += __shfl_xor(ss[r], 2);
                ss[r] += __shfl_xor(ss[r], 4);
                ss[r] += __shfl_xor(ss[r], 8);
            }
            if (nn < 4)
                sInv[s * 64 + tb + nn] = 1.f / fmaxf(sqrtf(ss[nn]), 1e-12f);
        }
        __syncthreads();

        // ===== attention: wave (g, hh), rows g*16..+15 of head 2p+hh =====
        {
            const int head = 2 * p + hh;
            const int i_base = g * 16 + quad * 4;

            // hoist the 16 dense-bias loads (independent of MFMAs)
            const float* btp = BT + head * 4096 + nn;
            float btv[16];
            #pragma unroll
            for (int ct = 0; ct < 4; ct++)
                #pragma unroll
                for (int r = 0; r < 4; r++)
                    btv[ct * 4 + r] = btp[(i_base + r) * 64 + ct * 16];
            const float scale = __expf(fminf(lsc[head], 4.605170185988092f));

            bf16x8 aq = *(const bf16x8*)(sQK + (g * 16 + nn) * 136 + hh * 32 + quad * 8);
            f32x4 S[4];
            #pragma unroll
            for (int ct = 0; ct < 4; ct++) {
                bf16x8 bk = *(const bf16x8*)(sQK + (ct * 16 + nn) * 136 + 64 + hh * 32 + quad * 8);
                S[ct] = mfma_bf16(aq, bk, zero4);
            }

            float invq[4];
            int ri[4];
            #pragma unroll
            for (int r = 0; r < 4; r++) {
                invq[r] = sInv[hh * 64 + i_base + r];
                ri[r] = masked ? region_of(wh, ww, i_base + r) : 0;
            }
            const float* invk = sInv + (2 + hh) * 64;

            float rowm[4] = {-3.0e38f, -3.0e38f, -3.0e38f, -3.0e38f};
            #pragma unroll
            for (int ct = 0; ct < 4; ct++) {
                int j = ct * 16 + nn;
                float ivk = invk[j];
                int rj = masked ? region_of(wh, ww, j) : 0;
                #pragma unroll
                for (int r = 0; r < 4; r++) {
                    float v = S[ct][r] * invq[r] * ivk * scale + btv[ct * 4 + r];
                    if (masked && (ri[r] != rj)) v += -100.f;
                    S[ct][r] = v;
                    rowm[r] = fmaxf(rowm[r], v);
                }
            }
            #pragma unroll
            for (int r = 0; r < 4; r++) {
                float m = rowm[r];
                m = fmaxf(m, __shfl_xor(m, 1));
                m = fmaxf(m, __shfl_xor(m, 2));
                m = fmaxf(m, __shfl_xor(m, 4));
                m = fmaxf(m, __shfl_xor(m, 8));
                rowm[r] = m;
            }
            float rsum[4] = {0.f, 0.f, 0.f, 0.f};
            #pragma unroll
            for (int ct = 0; ct < 4; ct++)
                #pragma unroll
                for (int r = 0; r < 4; r++) {
                    float e = __expf(S[ct][r] - rowm[r]);
                    S[ct][r] = e;
                    rsum[r] += e;
                }
            #pragma unroll
            for (int r = 0; r < 4; r++) {
                float sm = rsum[r];
                sm += __shfl_xor(sm, 1);
                sm += __shfl_xor(sm, 2);
                sm += __shfl_xor(sm, 4);
                sm += __shfl_xor(sm, 8);
                rsum[r] = 1.f / sm;
            }
            unsigned short* sPh = sP + hh * 4608;
            #pragma unroll
            for (int ct = 0; ct < 4; ct++)
                #pragma unroll
                for (int r = 0; r < 4; r++)
                    sPh[(i_base + r) * 72 + ct * 16 + nn] = f2bf(S[ct][r] * rsum[r]);

            bf16x8 ap0 = *(const bf16x8*)(sPh + (g * 16 + nn) * 72 + quad * 8);
            bf16x8 ap1 = *(const bf16x8*)(sPh + (g * 16 + nn) * 72 + 32 + quad * 8);
            #pragma unroll
            for (int ct2 = 0; ct2 < 2; ct2++) {
                bf16x8 bv0 = *(const bf16x8*)(sVt + (hh * 32 + ct2 * 16 + nn) * 72 + quad * 8);
                bf16x8 bv1 = *(const bf16x8*)(sVt + (hh * 32 + ct2 * 16 + nn) * 72 + 32 + quad * 8);
                f32x4 O = mfma_bf16(ap0, bv0, zero4);
                O = mfma_bf16(ap1, bv1, O);
                #pragma unroll
                for (int r = 0; r < 4; r++)
                    AO[((size_t)win * 64 + i_base + r) * 256 + head * 32 + ct2 * 16 + nn] = f2bf(O[r]);
            }
        }
    }
}

// ---------------------------------------------------------------------------
// k_proj: one block per window, 4 waves, 4 blocks/CU. Wave wv = row-tile.
// A fragments hoisted once (reused over 16 col-tiles); W double-buffered.
// ---------------------------------------------------------------------------
__global__ __launch_bounds__(256, 4) void k_proj(
    const unsigned short* __restrict__ AO,
    const unsigned short* __restrict__ Wp,
    const float* __restrict__ bp,
    const float* __restrict__ Xres,
    float* __restrict__ Xout,
    int shift)
{
    __shared__ __align__(16) unsigned short sO[64 * 264];
    __shared__ float sB[256];
    const int tid = threadIdx.x;
    const int wv = tid >> 6, lane = tid & 63, quad = lane >> 4, nn = lane & 15;
    const int win = blockIdx.x;
    const int bt = win >> 6, wh = (win >> 3) & 7, ww = win & 7;
    const f32x4 zero4 = {0.f, 0.f, 0.f, 0.f};

    {
        int tok = tid >> 2, part = tid & 3;
        const unsigned short* srcp = AO + ((size_t)win * 64 + tok) * 256 + part * 64;
        unsigned short* dstp = sO + tok * 264 + part * 64;
        #pragma unroll
        for (int c = 0; c < 64; c += 8)
            *(uint4*)(dstp + c) = *(const uint4*)(srcp + c);
        sB[tid] = bp[tid];
    }
    __syncthreads();

    // hoist A fragments: rows wv*16+nn, all 8 ks  (reused for all col-tiles)
    bf16x8 A[8];
    #pragma unroll
    for (int ks = 0; ks < 8; ks++)
        A[ks] = *(const bf16x8*)(sO + (wv * 16 + nn) * 264 + ks * 32 + quad * 8);

    // per-lane output row base offsets (4 rows)
    int ridx[4];
    #pragma unroll
    for (int r = 0; r < 4; r++) {
        int tok = wv * 16 + quad * 4 + r;
        int h = (wh * 8 + (tok >> 3) + shift) & 63;
        int w = (ww * 8 + (tok & 7) + shift) & 63;
        ridx[r] = (bt * 4096 + h * 64 + w) * 256;
    }

    const unsigned short* wbase = Wp + (size_t)nn * 256 + quad * 8;
    bf16x8 WB[2][8];
    #pragma unroll
    for (int ks = 0; ks < 8; ks++)
        WB[0][ks] = *(const bf16x8*)(wbase + ks * 32);

    #pragma unroll 2
    for (int ct = 0; ct < 16; ct++) {
        const int cb = ct & 1, nb = cb ^ 1;
        if (ct < 15) {
            const unsigned short* wp = wbase + (size_t)(ct + 1) * 16 * 256;
            #pragma unroll
            for (int ks = 0; ks < 8; ks++)
                WB[nb][ks] = *(const bf16x8*)(wp + ks * 32);
        }
        const int chan = ct * 16 + nn;
        float res[4];
        #pragma unroll
        for (int r = 0; r < 4; r++) res[r] = Xres[ridx[r] + chan];
        f32x4 acc = zero4;
        #pragma unroll
        for (int ks = 0; ks < 8; ks++)
            acc = mfma_bf16(A[ks], WB[cb][ks], acc);
        float bias = sB[chan];
        #pragma unroll
        for (int r = 0; r < 4; r++)
            Xout[ridx[r] + chan] = acc[r] + bias + res[r];
    }
}

// ---------------------------------------------------------------------------
extern "C" void kernel_launch(void* const* d_in, const int* in_sizes, int n_in,
                              void* d_out, int out_size, void* d_ws, size_t ws_size,
                              hipStream_t stream) {
    (void)in_sizes; (void)n_in; (void)out_size; (void)ws_size;

    const float* src        = (const float*)d_in[0];
    const float* a1_qkv_w   = (const float*)d_in[1];
    const float* a1_qkv_b   = (const float*)d_in[2];
    const float* a1_proj_w  = (const float*)d_in[3];
    const float* a1_proj_b  = (const float*)d_in[4];
    const float* a1_ls      = (const float*)d_in[5];
    const float* a1_w1      = (const float*)d_in[6];
    const float* a1_b1      = (const float*)d_in[7];
    const float* a1_w2      = (const float*)d_in[8];
    const float* a2_qkv_w   = (const float*)d_in[9];
    const float* a2_qkv_b   = (const float*)d_in[10];
    const float* a2_proj_w  = (const float*)d_in[11];
    const float* a2_proj_b  = (const float*)d_in[12];
    const float* a2_ls      = (const float*)d_in[13];
    const float* a2_w1      = (const float*)d_in[14];
    const float* a2_b1      = (const float*)d_in[15];
    const float* a2_w2      = (const float*)d_in[16];

    char* ws = (char*)d_ws;
    const size_t SZ_X = 134217728;  // 32*4096*256*4
    float* X0 = (float*)(ws);
    float* X1 = (float*)(ws + SZ_X);
    unsigned short* AO  = (unsigned short*)(ws + 2 * SZ_X);
    unsigned short* qw1 = (unsigned short*)(ws + 2 * SZ_X + 67108864);
    unsigned short* qw2 = qw1 + 196608;
    unsigned short* pw1 = qw2 + 196608;
    unsigned short* pw2 = pw1 + 65536;
    float* bt1 = (float*)(pw2 + 65536);
    float* bt2 = bt1 + 1800;
    float* BT1 = bt2 + 1800;
    float* BT2 = BT1 + 32768;

    k_setup<<<512, 256, 0, stream>>>(a1_qkv_w, a1_proj_w, a2_qkv_w, a2_proj_w,
                                     qw1, pw1, qw2, pw2);
    k_cpb<<<2, 256, 0, stream>>>(a1_w1, a1_b1, a1_w2, a2_w1, a2_b1, a2_w2, bt1, bt2);
    k_expand<<<256, 256, 0, stream>>>(bt1, bt2, BT1, BT2);
    t_in<<<dim3(128, 8, 32), 256, 0, stream>>>(src, X0);

    k_attn<<<2048, 512, 0, stream>>>(X0, qw1, a1_qkv_b, a1_ls, BT1, AO, 0, 0);
    k_proj<<<2048, 256, 0, stream>>>(AO, pw1, a1_proj_b, X0, X1, 0);
    k_attn<<<2048, 512, 0, stream>>>(X1, qw2, a2_qkv_b, a2_ls, BT2, AO, 4, 1);
    k_proj<<<2048, 256, 0, stream>>>(AO, pw2, a2_proj_b, X1, X0, 4);

    t_out<<<dim3(128, 8, 32), 256, 0, stream>>>(X0, (float*)d_out);
}